// Round 4
// baseline (70.616 us; speedup 1.0000x reference)
//
#include <hip/hip_runtime.h>
#include <math.h>

// ChADALINE: out[b,o] = sigmoid( (sum_i x[b,i]*W[i,o] + sum_i bias[i,o]) / IN )
// Choquet integral w/ cardinality measure == arithmetic mean; sort eliminated.
//
// R4: bias folded into the GEMM as 32 extra K-chunks with A == 1.0 (no load):
// sum_k bias[k,o] = ones . bias. prep is now a uniform pack kernel (no long
// latency chains); gemm has no bias path at all. Fragments packed in exact
// MFMA order, loaded global->VGPR, split-K-4, LDS reduce + sigmoid epilogue.

#define BATCH   256
#define IN_DIM  1024
#define OUT_DIM 1024

// ws layout (bytes)
#define APACK_OFF 0                    // [16 mt][32 s][64 lane][8] bf16 = 512 KB
#define WPACK_OFF (512 * 1024)         // [64 nt][64 s][64 lane][8] bf16 = 4 MB
                                       //   s<32: from w, s>=32: from bias

#define NWTASK_A   512                 // 16 mt * 32 s
#define NWTASK_W  4096                 // 64 nt * 64 s (w + bias)
#define NBLK_PREP ((NWTASK_A + NWTASK_W) / 4)   // 1152

typedef __bf16 bf16x8 __attribute__((ext_vector_type(8)));
typedef float  f32x4  __attribute__((ext_vector_type(4)));

__global__ __launch_bounds__(256) void chad_prep(
    const float* __restrict__ x,     // [BATCH, IN_DIM]
    const float* __restrict__ w,     // [IN_DIM, OUT_DIM]
    const float* __restrict__ bias,  // [IN_DIM, OUT_DIM]
    unsigned char* __restrict__ ws)
{
    __bf16* apack = (__bf16*)(ws + APACK_OFF);
    __bf16* wpack = (__bf16*)(ws + WPACK_OFF);

    const int t    = threadIdx.x;
    const int lane = t & 63;
    const int wv   = t >> 6;
    const int g    = blockIdx.x * 4 + wv;   // global wave-task id
    const int l16  = lane & 15;
    const int quad = lane >> 4;

    if (g < NWTASK_A) {
        // pack x[mt*16 + l16][s*32 + quad*8 + j] -> apack[g][lane][j]
        const int mt = g >> 5, s = g & 31;
        const float* src = x + (size_t)(mt * 16 + l16) * IN_DIM + s * 32 + quad * 8;
        const float4 v0 = *(const float4*)src;
        const float4 v1 = *(const float4*)(src + 4);
        bf16x8 o;
        o[0] = (__bf16)v0.x; o[1] = (__bf16)v0.y; o[2] = (__bf16)v0.z; o[3] = (__bf16)v0.w;
        o[4] = (__bf16)v1.x; o[5] = (__bf16)v1.y; o[6] = (__bf16)v1.z; o[7] = (__bf16)v1.w;
        *(bf16x8*)(apack + (size_t)g * 512 + lane * 8) = o;
    } else {
        // pack src[k + quad*8 + j][nt*16 + l16] -> wpack[nt*64+s][lane][j]
        // s<32: src=w, k=s*32; s>=32: src=bias, k=(s-32)*32
        const int wt = g - NWTASK_A;        // 0..4095
        const int nt = wt >> 6, s = wt & 63;
        const float* base = (s < 32) ? w : bias;
        const int k = (s & 31) * 32;
        const float* src = base + (size_t)(k + quad * 8) * OUT_DIM + nt * 16 + l16;
        bf16x8 o;
        #pragma unroll
        for (int j = 0; j < 8; ++j) o[j] = (__bf16)src[(size_t)j * OUT_DIM];
        *(bf16x8*)(wpack + (size_t)wt * 512 + lane * 8) = o;
    }
}

__global__ __launch_bounds__(256) void chad_gemm(
    const unsigned char* __restrict__ ws,
    float* __restrict__ out)          // [BATCH, OUT_DIM]
{
    const __bf16* apack = (const __bf16*)(ws + APACK_OFF);
    const __bf16* wpack = (const __bf16*)(ws + WPACK_OFF);

    __shared__ float red[4][64][4];   // [wave][lane][reg]

    const int t    = threadIdx.x;
    const int lane = t & 63;
    const int wv   = t >> 6;                 // split-K segment
    const int mt   = blockIdx.x >> 6;        // 0..15 row tile
    const int nt   = blockIdx.x & 63;        // 0..63 col tile

    const __bf16* ab  = apack + ((size_t)(mt * 32 + wv * 8) * 64 + lane) * 8;
    const __bf16* wb  = wpack + ((size_t)(nt * 64 + wv * 8) * 64 + lane) * 8;
    const __bf16* wb2 = wpack + ((size_t)(nt * 64 + 32 + wv * 8) * 64 + lane) * 8;

    // 24 independent, perfectly-coalesced dwordx4 loads issued up front
    bf16x8 af[8], bw[8], bb[8];
    #pragma unroll
    for (int i = 0; i < 8; ++i) {
        af[i] = *(const bf16x8*)(ab  + (size_t)i * 512);
        bw[i] = *(const bf16x8*)(wb  + (size_t)i * 512);
        bb[i] = *(const bf16x8*)(wb2 + (size_t)i * 512);
    }

    bf16x8 one8;
    #pragma unroll
    for (int j = 0; j < 8; ++j) one8[j] = (__bf16)1.0f;

    f32x4 acc = {0.f, 0.f, 0.f, 0.f};
    #pragma unroll
    for (int i = 0; i < 8; ++i)
        acc = __builtin_amdgcn_mfma_f32_16x16x32_bf16(af[i], bw[i], acc, 0, 0, 0);
    #pragma unroll
    for (int i = 0; i < 8; ++i)
        acc = __builtin_amdgcn_mfma_f32_16x16x32_bf16(one8, bb[i], acc, 0, 0, 0);

    *(f32x4*)&red[wv][lane][0] = acc;
    __syncthreads();

    // epilogue: thread t -> (row = t>>4, col = t&15) of the 16x16 tile.
    // C/D layout: value (row,col) lives in lane (row>>2)*16+col, reg row&3.
    const int row = t >> 4, col = t & 15;
    const int rl  = ((row >> 2) << 4) + col;
    const int rr  = row & 3;
    float v = red[0][rl][rr] + red[1][rl][rr] + red[2][rl][rr] + red[3][rl][rr];
    v *= (1.0f / (float)IN_DIM);
    out[(size_t)(mt * 16 + row) * OUT_DIM + nt * 16 + col] = 1.0f / (1.0f + __expf(-v));
}

extern "C" void kernel_launch(void* const* d_in, const int* in_sizes, int n_in,
                              void* d_out, int out_size, void* d_ws, size_t ws_size,
                              hipStream_t stream) {
    const float* x  = (const float*)d_in[0];
    const float* w  = (const float*)d_in[1];
    const float* b  = (const float*)d_in[2];
    float* out = (float*)d_out;

    chad_prep<<<NBLK_PREP, 256, 0, stream>>>(x, w, b, (unsigned char*)d_ws);
    chad_gemm<<<(BATCH / 16) * (OUT_DIM / 16), 256, 0, stream>>>(
        (const unsigned char*)d_ws, out);
}